// Round 12
// baseline (465.762 us; speedup 1.0000x reference)
//
#include <hip/hip_runtime.h>

// ---------------------------------------------------------------------------
// MORAL 2-layer GCN on MI355X — round 12.
//   Column-sliced aggregation: g/h1 stored slice-major [8][N][16 cols] so each
//   XCD's gather pool is 3.2MB (L2-resident) instead of 25.6MB (87% L2 miss).
//   slice = blockIdx&7 (matches empirical XCD round-robin; correctness is
//   mapping-independent). Wave = 8 dst-groups x 8 lanes x 2 cols; depth-4
//   unrolled gathers (32 outstanding 32B requests/wave); no cross-lane merge.
//   adj re-streamed per slice with nt hint. GEMM epilogue/A-load adjusted to
//   the sliced layout; agg2 writes row-major fp32 d_out (64B/dst lines).
//   partition/build/prep/init unchanged from r11.
// ---------------------------------------------------------------------------

typedef short bf16x8 __attribute__((ext_vector_type(8)));
typedef float f32x4 __attribute__((ext_vector_type(4)));
typedef unsigned short ushort_t;

__device__ __forceinline__ unsigned encf(float f) {
  unsigned u = __float_as_uint(f);
  return (u & 0x80000000u) ? ~u : (u | 0x80000000u);
}
__device__ __forceinline__ float decf(unsigned e) {
  unsigned u = (e & 0x80000000u) ? (e ^ 0x80000000u) : ~e;
  return __uint_as_float(u);
}
__device__ __forceinline__ ushort_t f2bf(float f) {
  unsigned u = __float_as_uint(f);
  u += 0x7FFF + ((u >> 16) & 1);  // RNE
  return (ushort_t)(u >> 16);
}
__device__ __forceinline__ float bf2f(ushort_t h) {
  return __uint_as_float((unsigned)h << 16);
}
__device__ __forceinline__ float bflo(unsigned v) {
  return __uint_as_float(v << 16);
}
__device__ __forceinline__ float bfhi(unsigned v) {
  return __uint_as_float(v & 0xFFFF0000u);
}

// ---- init + edge-dtype detect ----------------------------------------------
__global__ void init_kernel(const int* __restrict__ edges, int E, int* flag64,
                            unsigned* minenc, unsigned* maxenc, int* ovf_deg,
                            int* bcur, int* ctrl, int N) {
  int i = blockIdx.x * blockDim.x + threadIdx.x;
  if (i < 128) { minenc[i] = 0xFFFFFFFFu; maxenc[i] = 0u; }
  if (i < 2048) bcur[i] = 0;
  if (i < 32) ctrl[i] = 0;
  if (i < N) ovf_deg[i] = 0;
  if (blockIdx.x == 0) {
    __shared__ int any_nz;
    if (threadIdx.x == 0) any_nz = 0;
    __syncthreads();
    int idx = 2 * (int)threadIdx.x + 1;
    if (threadIdx.x < 128 && idx < 2 * E && edges[idx] != 0) any_nz = 1;
    __syncthreads();
    if (threadIdx.x == 0) *flag64 = !any_nz;
  }
}

__global__ void colminmax_kernel(const float* __restrict__ x, unsigned* minenc,
                                 unsigned* maxenc, int N) {
  int g = blockIdx.x * blockDim.x + threadIdx.x;
  int col = g & 127;
  int r0 = g >> 7;
  int nstream = (gridDim.x * blockDim.x) >> 7;
  float mn = 3.4e38f, mx = -3.4e38f;
  for (int r = r0; r < N; r += nstream) {
    float v = x[(size_t)r * 128 + col];
    mn = fminf(mn, v); mx = fmaxf(mx, v);
  }
  atomicMin(&minenc[col], encf(mn));
  atomicMax(&maxenc[col], encf(mx));
}

// Wt1[j][k] = bf16(s[k]*W1[k][j]); cvec[j] = sum_k mn[k]*float(Wt1[j][k])
__global__ __launch_bounds__(1024) void prep_kernel(
    const unsigned* __restrict__ minenc, const unsigned* __restrict__ maxenc,
    const float* __restrict__ W1, const float* __restrict__ W2,
    ushort_t* __restrict__ Wt1, ushort_t* __restrict__ Wt2,
    float* __restrict__ cvec, float* __restrict__ czero) {
  __shared__ float mn_s[128], s_s[128];
  __shared__ float csum[8][128];
  int tid = threadIdx.x;
  int j = tid & 127, kg = tid >> 7;
  if (tid < 128) {
    float mn = decf(minenc[tid]);
    float mx = decf(maxenc[tid]);
    mn_s[tid] = mn;
    s_s[tid] = 1.0f / ((mx > mn) ? (mx - mn) : 1.0f);
  }
  __syncthreads();
  ushort_t w1buf[16], w2buf[16];
  float c = 0.f;
#pragma unroll
  for (int kk = 0; kk < 16; ++kk) {
    int k = kg * 16 + kk;
    float wp = s_s[k] * W1[k * 128 + j];
    ushort_t wb = f2bf(wp);
    w1buf[kk] = wb;
    c += mn_s[k] * bf2f(wb);
    w2buf[kk] = f2bf(W2[k * 128 + j]);
  }
  {
    uint4* p1 = (uint4*)(Wt1 + j * 128 + kg * 16);
    uint4* p2 = (uint4*)(Wt2 + j * 128 + kg * 16);
    p1[0] = *(uint4*)&w1buf[0]; p1[1] = *(uint4*)&w1buf[8];
    p2[0] = *(uint4*)&w2buf[0]; p2[1] = *(uint4*)&w2buf[8];
  }
  csum[kg][j] = c;
  __syncthreads();
  if (tid < 128) {
    float t = 0.f;
#pragma unroll
    for (int x = 0; x < 8; ++x) t += csum[x][tid];
    cvec[tid] = t;
    czero[tid] = 0.f;
  }
}

// ---- Phase 1: MSB-radix partition (unchanged) -------------------------------
#define PITER 8
#define PCHUNK 2048

__global__ __launch_bounds__(256) void partition_kernel(
    const void* __restrict__ edges, int E, const int* __restrict__ flag64,
    unsigned* __restrict__ staging, int capx,
    int* __restrict__ ovf, int ovfcap, int* __restrict__ ovf_deg,
    int* __restrict__ bcur, int* __restrict__ ctrl,
    int srcbits, unsigned M, int width) {
  __shared__ unsigned pk_s[PCHUNK];
  __shared__ unsigned char bk_s[PCHUNK];
  __shared__ int hist[256], rbase[256], lcur[256];
  __shared__ int chunk_s;
  int xcd;
  asm volatile("s_getreg_b32 %0, hwreg(HW_REG_XCC_ID)" : "=s"(xcd));
  xcd &= 7;
  const int elo = (int)(((long long)E * xcd) >> 3);
  const int ehi = (int)(((long long)E * (xcd + 1)) >> 3);
  const int is64 = *flag64;
  const int tid = threadIdx.x;

  for (;;) {
    __syncthreads();
    if (tid == 0) chunk_s = atomicAdd(&ctrl[xcd], 1);
    hist[tid] = 0;
    __syncthreads();
    int base = elo + chunk_s * PCHUNK;
    if (base >= ehi) break;
    int cnt = ehi - base; if (cnt > PCHUNK) cnt = PCHUNK;
#pragma unroll
    for (int i = 0; i < PITER; ++i) {
      int idx = i * 256 + tid;
      if (idx < cnt) {
        int e = base + idx;
        int s, d;
        if (is64) {
          s = (int)__builtin_nontemporal_load((const long long*)edges + e);
          d = (int)__builtin_nontemporal_load((const long long*)edges + E + e);
        } else {
          s = __builtin_nontemporal_load((const int*)edges + e);
          d = __builtin_nontemporal_load((const int*)edges + E + e);
        }
        unsigned b = __umulhi((unsigned)d, M);
        int dloc = d - (int)b * width;
        pk_s[idx] = ((unsigned)dloc << srcbits) | (unsigned)s;
        bk_s[idx] = (unsigned char)b;
        atomicAdd(&hist[b], 1);
      }
    }
    __syncthreads();
    {
      int h = hist[tid];
      rbase[tid] = h ? atomicAdd(&bcur[xcd * 256 + tid], h) : 0;
      lcur[tid] = 0;
    }
    __syncthreads();
#pragma unroll
    for (int i = 0; i < PITER; ++i) {
      int idx = i * 256 + tid;
      if (idx < cnt) {
        int b = bk_s[idx];
        unsigned p = pk_s[idx];
        int j = atomicAdd(&lcur[b], 1);
        int pos = rbase[b] + j;
        if (pos < capx) {
          staging[((size_t)(xcd * 256 + b)) * capx + pos] = p;
        } else {
          int op = atomicAdd(&ctrl[8], 1);
          if (op < ovfcap) {
            int s = (int)(p & ((1u << srcbits) - 1u));
            int d = b * width + (int)(p >> srcbits);
            ovf[2 * op] = s; ovf[2 * op + 1] = d;
            atomicAdd(&ovf_deg[d], 1);
          }
        }
      }
    }
  }
}

// ---- Phase 2: per-bucket build (unchanged from r11) -------------------------
#define WMAX 512
#define BLDS 12288

__global__ __launch_bounds__(256) void build_kernel(
    const unsigned* __restrict__ staging, int capx,
    const int* __restrict__ bcur, const int* __restrict__ ovf_deg,
    const int* __restrict__ ovf, int ovfcap, const int* __restrict__ ctrl,
    int* __restrict__ rowptr, int* __restrict__ gcursor,
    float* __restrict__ dinv, int* __restrict__ adj,
    int N, int E, int srcbits, int width) {
  __shared__ int cntS[WMAX], scn[WMAX], lcur[WMAX];
  __shared__ unsigned items[BLDS];
  __shared__ int sbase;
  int b = blockIdx.x;
  int tid = threadIdx.x;
  int nlo = b * width;
  int wcnt = N - nlo; if (wcnt > width) wcnt = width; if (wcnt < 0) wcnt = 0;

  for (int i = tid; i < WMAX; i += 256) cntS[i] = 0;

  int t0 = 0;
#pragma unroll
  for (int x = 0; x < 8; ++x) t0 += bcur[x * 256 + tid];
  scn[tid] = t0;
  __syncthreads();
  for (int off = 1; off < 256; off <<= 1) {
    int v = (tid >= off) ? scn[tid - off] : 0;
    __syncthreads();
    scn[tid] += v;
    __syncthreads();
  }
  if (tid == b) sbase = scn[b] - t0;
  __syncthreads();
  int base = sbase;

  int lens[8], offx[8], tot = 0;
#pragma unroll
  for (int x = 0; x < 8; ++x) {
    int l = bcur[x * 256 + b]; if (l > capx) l = capx;
    lens[x] = l; offx[x] = tot; tot += l;
  }
  bool fits = (tot <= BLDS);

  for (int x = 0; x < 8; ++x) {
    const unsigned* sp = staging + ((size_t)(x * 256 + b)) * capx;
    int len = lens[x], ox = offx[x];
    for (int i = tid; i < len; i += 256) {
      unsigned p = sp[i];
      if (fits) items[ox + i] = p;
      atomicAdd(&cntS[p >> srcbits], 1);
    }
  }
  __syncthreads();

  for (int i = tid; i < WMAX; i += 256)
    scn[i] = cntS[i] + ((i < wcnt) ? ovf_deg[nlo + i] : 0);
  __syncthreads();
  for (int off = 1; off < WMAX; off <<= 1) {
    int i0 = tid, i1 = tid + 256;
    int v0 = (i0 >= off) ? scn[i0 - off] : 0;
    int v1 = (i1 >= off) ? scn[i1 - off] : 0;
    __syncthreads();
    scn[i0] += v0; scn[i1] += v1;
    __syncthreads();
  }

  for (int i = tid; i < WMAX; i += 256) {
    int ov = (i < wcnt) ? ovf_deg[nlo + i] : 0;
    int orig = cntS[i] + ov;
    int ex = scn[i] - orig;
    lcur[i] = ex;
    if (i < wcnt) {
      rowptr[nlo + i] = base + ex;
      gcursor[nlo + i] = base + ex + cntS[i];
      dinv[nlo + i] = rsqrtf((float)orig + 1.0f);
    }
  }
  if (b == gridDim.x - 1 && tid == 0) rowptr[N] = E;
  __syncthreads();

  if (fits) {
    for (int i = tid; i < tot; i += 256) {
      unsigned p = items[i];
      int pos = atomicAdd(&lcur[p >> srcbits], 1);
      adj[base + pos] = (int)(p & ((1u << srcbits) - 1u));
    }
  } else {
    for (int x = 0; x < 8; ++x) {
      const unsigned* sp = staging + ((size_t)(x * 256 + b)) * capx;
      int len = lens[x];
      for (int i = tid; i < len; i += 256) {
        unsigned p = sp[i];
        int pos = atomicAdd(&lcur[p >> srcbits], 1);
        adj[base + pos] = (int)(p & ((1u << srcbits) - 1u));
      }
    }
  }
  __syncthreads();

  int ovlen = ctrl[8]; if (ovlen > ovfcap) ovlen = ovfcap;
  if (ovlen > 0) {
    int nhi = nlo + wcnt;
    for (int i = tid; i < ovlen; i += 256) {
      int s = ovf[2 * i], d = ovf[2 * i + 1];
      if (d >= nlo && d < nhi) {
        int pos = atomicAdd(&gcursor[d], 1);
        adj[pos] = s;
      }
    }
  }
}

// ---- MFMA GEMM: g_sliced = (X @ Wt^T - cvec) * dinv[row] --------------------
// Output layout: g[((col>>4)*N + row)*16 + (col&15)]  (slice-major).
// XSLICED=0: X is row-major fp32.  XSLICED=1: X is sliced bf16 (h1).
template <int XSLICED>
__global__ __launch_bounds__(256) void gemm_mfma_kernel(
    const void* __restrict__ Xv, const ushort_t* __restrict__ Wtg,
    const float* __restrict__ cvec, const float* __restrict__ dinv,
    ushort_t* __restrict__ g, int N) {
  __shared__ ushort_t wt[128 * 128];  // XOR-swizzled
  int t = threadIdx.x;
  for (int c = t; c < 2048; c += 256) {
    int j = c >> 4;
    int ko = (c & 15) << 4;
    uint4 v = *(const uint4*)(Wtg + j * 128 + (ko >> 1));
    *(uint4*)((char*)wt + j * 256 + (ko ^ ((j & 7) << 4))) = v;
  }
  __syncthreads();

  int lane = t & 63, w = t >> 6;
  int lrow = lane & 15;
  int lk = lane >> 4;
  int rowA = blockIdx.x * 64 + w * 16 + lrow;
  int rA = (rowA < N) ? rowA : (N - 1);

  f32x4 acc[8];
#pragma unroll
  for (int i = 0; i < 8; ++i) acc[i] = (f32x4){0.f, 0.f, 0.f, 0.f};

#pragma unroll
  for (int ks = 0; ks < 4; ++ks) {
    int k0 = ks * 32;
    bf16x8 a;
    if (XSLICED) {
      int k = k0 + lk * 8;
      const ushort_t* hp =
          (const ushort_t*)Xv + ((size_t)(k >> 4) * N + rA) * 16 + (k & 15);
      a = *(const bf16x8*)hp;
    } else {
      const float* xp = (const float*)Xv + (size_t)rA * 128 + k0 + lk * 8;
      float4 f0 = *(const float4*)xp;
      float4 f1 = *(const float4*)(xp + 4);
      bf16x8 tmp;
      tmp[0] = (short)f2bf(f0.x); tmp[1] = (short)f2bf(f0.y);
      tmp[2] = (short)f2bf(f0.z); tmp[3] = (short)f2bf(f0.w);
      tmp[4] = (short)f2bf(f1.x); tmp[5] = (short)f2bf(f1.y);
      tmp[6] = (short)f2bf(f1.z); tmp[7] = (short)f2bf(f1.w);
      a = tmp;
    }
    int koff = k0 * 2 + lk * 16;
#pragma unroll
    for (int tl = 0; tl < 8; ++tl) {
      int j = tl * 16 + lrow;
      bf16x8 bfr = *(const bf16x8*)((const char*)wt + j * 256 + (koff ^ ((j & 7) << 4)));
      acc[tl] = __builtin_amdgcn_mfma_f32_16x16x32_bf16(a, bfr, acc[tl], 0, 0, 0);
    }
  }

  int robase = blockIdx.x * 64 + w * 16 + (lane >> 4) * 4;
#pragma unroll
  for (int j = 0; j < 4; ++j) {
    int row = robase + j;
    if (row < N) {
      float dv = dinv[row];
#pragma unroll
      for (int tl = 0; tl < 8; ++tl) {
        // col = tl*16 + lrow  ->  slice = tl, col_in_slice = lrow
        float o = (acc[tl][j] - cvec[tl * 16 + lrow]) * dv;
        g[((size_t)tl * N + row) * 16 + lrow] = f2bf(o);
      }
    }
  }
}

// ---- aggregate (sliced): block handles slice = bid&7 for 32 dsts ------------
// Per wave: 8 dst-groups x 8 lanes x 2 cols; depth-4 gather unroll.
// out[d] = act(dinv[d] * (g[d] + sum_{s in adj[d]} g[s]) + b)  (per slice)
template <int LAYER2>
__global__ __launch_bounds__(256) void aggregate_kernel(
    const int* __restrict__ rowptr, const int* __restrict__ adj,
    const ushort_t* __restrict__ g, const float* __restrict__ dinv,
    const float* __restrict__ b, void* __restrict__ out, int N) {
  int slice = blockIdx.x & 7;
  int tid = threadIdx.x;
  int d = (blockIdx.x >> 3) * 32 + (tid >> 3);  // 32 dst-groups per block
  if (d >= N) return;
  int l8 = tid & 7;  // cols slice*16 + l8*2 .. +1

  const ushort_t* gs = g + (size_t)slice * N * 16 + l8 * 2;

  // self loop
  unsigned sv = *(const unsigned*)(gs + (size_t)d * 16);
  float a0 = bflo(sv), a1 = bfhi(sv);

  int beg = rowptr[d], end = rowptr[d + 1];
  int i = beg;
  for (; i + 3 < end; i += 4) {
    int n0 = __builtin_nontemporal_load(adj + i);
    int n1 = __builtin_nontemporal_load(adj + i + 1);
    int n2 = __builtin_nontemporal_load(adj + i + 2);
    int n3 = __builtin_nontemporal_load(adj + i + 3);
    unsigned v0 = *(const unsigned*)(gs + (size_t)n0 * 16);
    unsigned v1 = *(const unsigned*)(gs + (size_t)n1 * 16);
    unsigned v2 = *(const unsigned*)(gs + (size_t)n2 * 16);
    unsigned v3 = *(const unsigned*)(gs + (size_t)n3 * 16);
    a0 += (bflo(v0) + bflo(v1)) + (bflo(v2) + bflo(v3));
    a1 += (bfhi(v0) + bfhi(v1)) + (bfhi(v2) + bfhi(v3));
  }
  for (; i < end; ++i) {
    int n = __builtin_nontemporal_load(adj + i);
    unsigned v = *(const unsigned*)(gs + (size_t)n * 16);
    a0 += bflo(v); a1 += bfhi(v);
  }

  float dv = dinv[d];
  const float2 bb = *(const float2*)&b[slice * 16 + l8 * 2];
  float o0 = dv * a0 + bb.x;
  float o1 = dv * a1 + bb.y;
  if (!LAYER2) {  // relu + sliced bf16 store (4B/lane, 32B/dst contiguous)
    o0 = fmaxf(o0, 0.f); o1 = fmaxf(o1, 0.f);
    unsigned ov = (unsigned)f2bf(o0) | ((unsigned)f2bf(o1) << 16);
    *(unsigned*)((ushort_t*)out + ((size_t)slice * N + d) * 16 + l8 * 2) = ov;
  } else {  // row-major fp32 d_out (8B/lane, 64B/dst contiguous)
    float2 w; w.x = o0; w.y = o1;
    *(float2*)((float*)out + (size_t)d * 128 + slice * 16 + l8 * 2) = w;
  }
}

extern "C" void kernel_launch(void* const* d_in, const int* in_sizes, int n_in,
                              void* d_out, int out_size, void* d_ws, size_t ws_size,
                              hipStream_t stream) {
  const float* features = (const float*)d_in[0];
  const float* W1 = (const float*)d_in[1];
  const float* b1 = (const float*)d_in[2];
  const float* W2 = (const float*)d_in[3];
  const float* b2 = (const float*)d_in[4];
  const void* edges = d_in[5];
  const int N = in_sizes[0] / 128;
  const int E = in_sizes[5] / 2;

  int srcbits = 1; while ((1LL << srcbits) < (long long)N) srcbits++;
  const int width = (N + 255) / 256;
  const unsigned M = (unsigned)(0x100000000ULL / (unsigned)width + 1);
  const int capx = (E / 2048) * 3 + 256;
  const int ovfcap = E / 4;

  float* ws = (float*)d_ws;
  size_t off = 0;
  ushort_t* gbuf = (ushort_t*)(ws + off);  off += (size_t)N * 64;  // sliced bf16
  ushort_t* h1 = (ushort_t*)(ws + off);    off += (size_t)N * 64;  // sliced bf16
  int* rowptr = (int*)(ws + off);      off += N + 4;
  int* gcursor = (int*)(ws + off);     off += N + 4;
  int* adj = (int*)(ws + off);         off += E;
  int* ovf_deg = (int*)(ws + off);     off += N + 4;
  float* dinv = ws + off;              off += N + 4;
  unsigned* minenc = (unsigned*)(ws + off); off += 128;
  unsigned* maxenc = (unsigned*)(ws + off); off += 128;
  ushort_t* Wt1 = (ushort_t*)(ws + off);    off += 128 * 64;
  ushort_t* Wt2 = (ushort_t*)(ws + off);    off += 128 * 64;
  float* cvec = ws + off;              off += 128;
  float* czero = ws + off;             off += 128;
  int* flag64 = (int*)(ws + off);      off += 4;
  int* ctrl = (int*)(ws + off);        off += 32;
  int* bcur = (int*)(ws + off);        off += 2048;
  unsigned* staging = (unsigned*)(ws + off); off += (size_t)2048 * capx;
  int* ovf = (int*)(ws + off);         off += 2 * (size_t)ovfcap;

  float* outf = (float*)d_out;
  const int aggGrid = 8 * ((N + 31) / 32);

  // ---- graph + weight prep ----
  init_kernel<<<(N + 255) / 256, 256, 0, stream>>>(
      (const int*)edges, E, flag64, minenc, maxenc, ovf_deg, bcur, ctrl, N);
  colminmax_kernel<<<512, 256, 0, stream>>>(features, minenc, maxenc, N);
  prep_kernel<<<1, 1024, 0, stream>>>(minenc, maxenc, W1, W2, Wt1, Wt2, cvec, czero);
  partition_kernel<<<1024, 256, 0, stream>>>(edges, E, flag64, staging, capx,
                                             ovf, ovfcap, ovf_deg, bcur, ctrl,
                                             srcbits, M, width);
  build_kernel<<<256, 256, 0, stream>>>(staging, capx, bcur, ovf_deg,
                                        ovf, ovfcap, ctrl,
                                        rowptr, gcursor, dinv, adj,
                                        N, E, srcbits, width);

  // ---- layer 1 ----
  gemm_mfma_kernel<0><<<(N + 63) / 64, 256, 0, stream>>>(
      features, Wt1, cvec, dinv, gbuf, N);
  aggregate_kernel<0><<<aggGrid, 256, 0, stream>>>(
      rowptr, adj, gbuf, dinv, b1, h1, N);

  // ---- layer 2 ----
  gemm_mfma_kernel<1><<<(N + 63) / 64, 256, 0, stream>>>(
      h1, Wt2, czero, dinv, gbuf, N);
  aggregate_kernel<1><<<aggGrid, 256, 0, stream>>>(
      rowptr, adj, gbuf, dinv, b2, outf, N);
}